// Round 10
// baseline (16420.830 us; speedup 1.0000x reference)
//
#include <hip/hip_runtime.h>
#include <hip/hip_bf16.h>

#define TT 2048
#define BB 32
#define DD 256
#define HH 512
#define NWG 32      // workgroups per layer
#define UPW 16      // hidden units per workgroup
#define RING 64     // ring depth (power of 2); L0 lead throttled < 56

typedef unsigned long long u64;
typedef unsigned u32;
using f32x4 = __attribute__((ext_vector_type(4))) float;
using s16x8 = __attribute__((ext_vector_type(8))) short;

// ALL cross-wg traffic is relaxed agent-scope (MALL). Law from r1-r9:
// cache-maintenance fences (r1), sc0/XCD-L2 sync (r4/r5/r9), oversized
// tagged arrays (r6), and ungated polling (r3/r7) all fail; what works is
// small L3-resident tagged rings + a cheap wave0 flag poll (r2) and
// bulk data moved exactly once (r8 minus its all-thread poll + LDS bugs).
// Tagged u64 = [h_even | h_odd<<16 | t<<32]; tags are the correctness
// authority (no drains, no fences; flag/data races are benign).
__device__ __attribute__((aligned(16))) u64 g_r0[RING][BB][HH / 2];   // 4 MB
__device__ __attribute__((aligned(16))) u64 g_r1[RING][BB][HH / 2];   // 4 MB
__device__ __attribute__((aligned(16))) __hip_bfloat16 g_xb[BB][TT][DD];
__device__ __attribute__((aligned(16))) float g_h1f[BB][HH];
__device__ int g_f0[NWG];   // per-wg monotonic flags (one 128B line)
__device__ int g_f1[NWG];
__device__ int g_prog1;     // L1 progress (throttles L0 lead vs RING)

#define RSLOT (BB * (HH / 2))   // u64 words per ring slot (8192)
#define GBS 68                  // gbuf stride (68*4 mod 128 != 0: conflict-free)

__device__ __forceinline__ short f2bf(float f) {
    union { float f; unsigned u; } v; v.f = f;
    unsigned r = v.u + 0x7fffu + ((v.u >> 16) & 1u);  // RNE
    return (short)(r >> 16);
}
__device__ __forceinline__ float sigm(float x) { return 1.f / (1.f + __expf(-x)); }
__device__ __forceinline__ float tanh_f(float x) { return 1.f - 2.f / (__expf(2.f * x) + 1.f); }

__device__ __forceinline__ u64 ald(const u64* p) {
    return __hip_atomic_load(p, __ATOMIC_RELAXED, __HIP_MEMORY_SCOPE_AGENT);
}
__device__ __forceinline__ int aldi(const int* p) {
    return __hip_atomic_load(p, __ATOMIC_RELAXED, __HIP_MEMORY_SCOPE_AGENT);
}

// ---------------------------------------------------------------------------
// Step: wave0 flag-poll -> b1 -> issue own(+cross) bulk loads once ->
//       stage x / tag-verify+stage -> b2 -> MFMA -> gbuf -> b3 ->
//       gates -> tagged publish -> flag (no drain).
// ---------------------------------------------------------------------------
template <int LAYER>
__device__ void scan_layer(char* smem, int wgk,
                           const float* __restrict__ Wih, const float* __restrict__ Whh,
                           const float* __restrict__ bih, const float* __restrict__ bhh) {
    constexpr int KIN = (LAYER == 0) ? DD : HH;  // 256 / 512
    constexpr int KL  = KIN + HH;                // 768 / 1024
    constexpr int QK  = KL / 4;
    constexpr int NKQ = QK / 32;
    constexpr int ROWB = 2048;                   // LDS A row stride (bytes)

    const int tid  = threadIdx.x;
    const int wave = tid >> 6;
    const int lane = tid & 63;
    const int m    = wave & 1;
    const int q    = wave >> 1;
    const int u16i = lane & 15;
    const int hi   = lane >> 4;

    // ---- weights into registers (one-time) --------------------------------
    s16x8 wreg[NKQ * 4];
    {
        const int unit = wgk * UPW + u16i;
#pragma unroll
        for (int ks = 0; ks < NKQ; ++ks) {
#pragma unroll
            for (int gt = 0; gt < 4; ++gt) {
                const int k = q * QK + ks * 32 + hi * 8;
                const float* src = (k < KIN)
                    ? (Wih + (size_t)(gt * HH + unit) * KIN + k)
                    : (Whh + (size_t)(gt * HH + unit) * HH + (k - KIN));
                s16x8 w;
#pragma unroll
                for (int j = 0; j < 8; ++j) w[j] = f2bf(src[j]);
                wreg[ks * 4 + gt] = w;
            }
        }
    }

    const int eb = tid >> 4;
    const int eu = tid & 15;
    const int unit_g = wgk * UPW + eu;
    float bias[4];
#pragma unroll
    for (int gt = 0; gt < 4; ++gt)
        bias[gt] = bih[gt * HH + unit_g] + bhh[gt * HH + unit_g];
    float c = 0.f;

    const int sb = tid >> 4;   // batch row this thread stages
    const int sk = tid & 15;   // group column

    float* gbuf = (float*)(smem + 65536);  // disjoint from A region

    const u64* ownring = (LAYER == 0) ? &g_r0[0][0][0] : &g_r1[0][0][0];

    for (int t = 0; t < TT; ++t) {
        // ---- [T] L0 ring-overwrite throttle (off critical path) -----------
        if (LAYER == 0 && (t & 15) == 0 && t >= 48) {
            int it = 0;
            while (aldi(&g_prog1) < t - 40) {
                if (++it > (1 << 16)) break;
                __builtin_amdgcn_s_sleep(4);
            }
        }

        // ---- [B] wave0-only flag poll (1-2 MALL lines per wg per round) ---
        if (wave == 0) {
            int rounds = 0;
            for (;;) {
                bool ok = true;
                if (LAYER == 0) {
                    if (lane < NWG) ok = (aldi(&g_f0[lane]) >= t);
                } else {
                    if (lane < NWG)      ok = (aldi(&g_f1[lane]) >= t);
                    else                 ok = (aldi(&g_f0[lane - NWG]) >= t + 1);
                }
                if (__all(ok)) break;
                if (++rounds > (1 << 15)) break;  // escape: visible failure beats hang
                if (rounds > 8) __builtin_amdgcn_s_sleep(1);
            }
        }
        __syncthreads();  // b1: whole wg gated

        // ---- [A] issue own (+cross) bulk loads once, back-to-back ---------
        u64 ow[16];
        const u64* op = ownring + (size_t)(t & (RING - 1)) * RSLOT + (size_t)sb * (HH / 2);
#pragma unroll
        for (int g = 0; g < 4; ++g)
#pragma unroll
            for (int j = 0; j < 4; ++j)
                ow[g * 4 + j] = ald(op + (sk + 16 * g) * 4 + j);

        u64 cw[16];
        const u64* cp = &g_r0[(t + 1) & (RING - 1)][sb][0];
        if constexpr (LAYER == 1) {
#pragma unroll
            for (int g = 0; g < 4; ++g)
#pragma unroll
                for (int j = 0; j < 4; ++j)
                    cw[g * 4 + j] = ald(cp + (sk + 16 * g) * 4 + j);
        }

        // ---- [C] L0: stage x (plain cached loads; overlaps load RT) -------
        if constexpr (LAYER == 0) {
#pragma unroll
            for (int g = 0; g < 2; ++g) {
                const int kg = sk + 16 * g;
                s16x8 v = *(const s16x8*)&g_xb[sb][t][kg * 8];
                *(s16x8*)(smem + sb * ROWB + ((kg * 16) ^ ((sb & 7) << 4))) = v;
            }
        }

        // ---- [D] own tag-verify (expect clean) + masked retry, stage ------
        {
            const u32 tago = (u32)t;
            int rounds = 0;
            for (;;) {
                u32 bad = 0;
#pragma unroll
                for (int w = 0; w < 16; ++w)
                    if ((u32)(ow[w] >> 32) != tago) bad |= (1u << w);
                if (!bad) break;
                if (++rounds > (1 << 14)) break;  // wrong answer beats hang
                if (rounds > 2) __builtin_amdgcn_s_sleep(1);
#pragma unroll
                for (int w = 0; w < 16; ++w)
                    if (bad & (1u << w))
                        ow[w] = ald(op + (sk + 16 * (w >> 2)) * 4 + (w & 3));
            }
#pragma unroll
            for (int g = 0; g < 4; ++g) {
                const int kg = sk + 16 * (g + (LAYER == 0 ? 2 : 4));
                s16x8 v;
#pragma unroll
                for (int j = 0; j < 4; ++j) {
                    v[2 * j]     = (short)(u32)ow[g * 4 + j];
                    v[2 * j + 1] = (short)((u32)ow[g * 4 + j] >> 16);
                }
                *(s16x8*)(smem + sb * ROWB + ((kg * 16) ^ ((sb & 7) << 4))) = v;
            }
        }

        // ---- [E] L1: cross tag-verify + masked retry, stage ---------------
        if constexpr (LAYER == 1) {
            const u32 tagc = (u32)(t + 1);
            int rounds = 0;
            for (;;) {
                u32 bad = 0;
#pragma unroll
                for (int w = 0; w < 16; ++w)
                    if ((u32)(cw[w] >> 32) != tagc) bad |= (1u << w);
                if (!bad) break;
                if (++rounds > (1 << 14)) break;
                if (rounds > 2) __builtin_amdgcn_s_sleep(1);
#pragma unroll
                for (int w = 0; w < 16; ++w)
                    if (bad & (1u << w))
                        cw[w] = ald(cp + (sk + 16 * (w >> 2)) * 4 + (w & 3));
            }
#pragma unroll
            for (int g = 0; g < 4; ++g) {
                const int kg = sk + 16 * g;
                s16x8 v;
#pragma unroll
                for (int j = 0; j < 4; ++j) {
                    v[2 * j]     = (short)(u32)cw[g * 4 + j];
                    v[2 * j + 1] = (short)((u32)cw[g * 4 + j] >> 16);
                }
                *(s16x8*)(smem + sb * ROWB + ((kg * 16) ^ ((sb & 7) << 4))) = v;
            }
        }

        __syncthreads();  // b2: A tile complete

        // ---- MFMA ----------------------------------------------------------
        f32x4 acc[4] = {{0,0,0,0},{0,0,0,0},{0,0,0,0},{0,0,0,0}};
        {
            const int arow = m * 16 + u16i;
            const char* abase = smem + arow * ROWB;
            const int aswz = (arow & 7) << 4;
#pragma unroll
            for (int ks = 0; ks < NKQ; ++ks) {
                const int off = (q * QK + ks * 32 + hi * 8) * 2;
                s16x8 a = *(const s16x8*)(abase + (off ^ aswz));
#pragma unroll
                for (int gt = 0; gt < 4; ++gt)
                    acc[gt] = __builtin_amdgcn_mfma_f32_16x16x32_bf16(a, wreg[ks * 4 + gt], acc[gt], 0, 0, 0);
            }
        }

        // ---- partials -> gbuf (disjoint region) ----------------------------
#pragma unroll
        for (int gt = 0; gt < 4; ++gt) {
#pragma unroll
            for (int r = 0; r < 4; ++r) {
                const int b = m * 16 + hi * 4 + r;  // C row = (lane>>4)*4 + reg
                gbuf[(q * BB + b) * GBS + gt * 16 + u16i] = acc[gt][r];
            }
        }

        __syncthreads();  // b3: partials complete

        // ---- gates, state, tagged publish + flag (no drain) ----------------
        {
            float gv[4];
#pragma unroll
            for (int gt = 0; gt < 4; ++gt) {
                float s = bias[gt];
#pragma unroll
                for (int qq = 0; qq < 4; ++qq) s += gbuf[(qq * BB + eb) * GBS + gt * 16 + eu];
                gv[gt] = s;
            }
            const float ig = sigm(gv[0]);
            const float fg = sigm(gv[1]);
            const float gg = tanh_f(gv[2]);
            const float og = sigm(gv[3]);
            c = fg * c + ig * gg;
            const float h = og * tanh_f(c);
            const u32 hu = (u32)(unsigned short)f2bf(h);
            const u32 other = __shfl_xor(hu, 1);
            if (LAYER == 1 && t == TT - 1) g_h1f[eb][unit_g] = h;
            if ((eu & 1) == 0) {
                const u64 wv = (u64)(hu | (other << 16)) | ((u64)(u32)(t + 1) << 32);
                u64* dst = (u64*)ownring + (size_t)((t + 1) & (RING - 1)) * RSLOT
                         + (size_t)eb * (HH / 2) + unit_g / 2;
                __hip_atomic_store(dst, wv, __ATOMIC_RELAXED, __HIP_MEMORY_SCOPE_AGENT);
            }
            // flag right after data stores (program order); tags cover races.
            if (tid == 0) {
                int* f = (LAYER == 0) ? &g_f0[wgk] : &g_f1[wgk];
                __hip_atomic_store(f, t + 1, __ATOMIC_RELAXED, __HIP_MEMORY_SCOPE_AGENT);
            }
            if (LAYER == 1 && wgk == 0 && tid == 0)
                __hip_atomic_store(&g_prog1, t + 1, __ATOMIC_RELAXED, __HIP_MEMORY_SCOPE_AGENT);
        }
    }
}

__global__ __launch_bounds__(512) void lstm_scan(
    const float* __restrict__ Wih0, const float* __restrict__ Whh0,
    const float* __restrict__ bih0, const float* __restrict__ bhh0,
    const float* __restrict__ Wih1, const float* __restrict__ Whh1,
    const float* __restrict__ bih1, const float* __restrict__ bhh1) {
    __shared__ __attribute__((aligned(16))) char smem[65536 + 4 * BB * GBS * 4];
    const int layer = blockIdx.x >> 5;
    const int wgk   = blockIdx.x & (NWG - 1);
    if (layer == 0) scan_layer<0>(smem, wgk, Wih0, Whh0, bih0, bhh0);
    else            scan_layer<1>(smem, wgk, Wih1, Whh1, bih1, bhh1);
}

// prep: zero rings (stale tags alias at wrap), flags, progress; cast x->bf16.
__global__ void prep_kernel(const float* __restrict__ x) {
    const int wg = blockIdx.x;
    const int tid = threadIdx.x;
    if (wg == 0) {
        if (tid == 0) g_prog1 = 0;
        if (tid < NWG) { g_f0[tid] = 0; g_f1[tid] = 0; }
    }
    if (wg >= 2) {
        const size_t i = (size_t)(wg - 2) * 256 + tid;  // one 8-float group
        const float4* xs = (const float4*)x + i * 2;
        const float4 a = xs[0], b = xs[1];
        s16x8 v;
        v[0] = f2bf(a.x); v[1] = f2bf(a.y); v[2] = f2bf(a.z); v[3] = f2bf(a.w);
        v[4] = f2bf(b.x); v[5] = f2bf(b.y); v[6] = f2bf(b.z); v[7] = f2bf(b.w);
        ((s16x8*)&g_xb[0][0][0])[i] = v;
        ulonglong2* p0 = (ulonglong2*)&g_r0[0][0][0];
        ulonglong2* p1 = (ulonglong2*)&g_r1[0][0][0];
        const size_t n = (size_t)RING * RSLOT / 2;  // 262144 x 16B each
        const ulonglong2 z = {0ull, 0ull};
        for (size_t k = i; k < n; k += (size_t)8192 * 256) { p0[k] = z; p1[k] = z; }
    }
}

__global__ void out_kernel(const float* __restrict__ Wout, const float* __restrict__ bout,
                           float* __restrict__ out) {
    const int b = blockIdx.x;
    const int o = threadIdx.x;
    const float4* h4 = (const float4*)&g_h1f[b][0];
    const float4* w4 = (const float4*)(Wout + (size_t)o * HH);
    float s = bout[o];
    for (int k = 0; k < HH / 4; ++k) {
        const float4 a = h4[k], w = w4[k];
        s += a.x * w.x + a.y * w.y + a.z * w.z + a.w * w.w;
    }
    out[b * 256 + o] = s;
}

extern "C" void kernel_launch(void* const* d_in, const int* in_sizes, int n_in,
                              void* d_out, int out_size, void* d_ws, size_t ws_size,
                              hipStream_t stream) {
    const float* x    = (const float*)d_in[0];
    const float* Wih0 = (const float*)d_in[1];
    const float* Whh0 = (const float*)d_in[2];
    const float* bih0 = (const float*)d_in[3];
    const float* bhh0 = (const float*)d_in[4];
    const float* Wih1 = (const float*)d_in[5];
    const float* Whh1 = (const float*)d_in[6];
    const float* bih1 = (const float*)d_in[7];
    const float* bhh1 = (const float*)d_in[8];
    const float* Wout = (const float*)d_in[9];
    const float* bout = (const float*)d_in[10];
    float* out = (float*)d_out;

    hipLaunchKernelGGL(prep_kernel, dim3(2 + 8192), dim3(256), 0, stream, x);
    hipLaunchKernelGGL(lstm_scan, dim3(2 * NWG), dim3(512), 0, stream,
                       Wih0, Whh0, bih0, bhh0, Wih1, Whh1, bih1, bhh1);
    hipLaunchKernelGGL(out_kernel, dim3(BB), dim3(256), 0, stream, Wout, bout, out);
}